// Round 2
// baseline (216.359 us; speedup 1.0000x reference)
//
#include <hip/hip_runtime.h>
#include <hip/hip_bf16.h>
#include <math.h>

#define NH 8
#define NP 4
#define DD 64
#define DM 512

typedef unsigned short u16;
typedef unsigned int u32;

using frag_ab = __attribute__((ext_vector_type(8))) short;  // 8 bf16 (4 VGPRs)
using f32x4   = __attribute__((ext_vector_type(4))) float;  // 4 fp32 acc

__device__ __forceinline__ u16 f2b(float f) {               // fp32 -> bf16 (RNE)
    u32 u = __float_as_uint(f);
    u32 r = (u + 0x7FFFu + ((u >> 16) & 1u)) >> 16;
    return (u16)r;
}
__device__ __forceinline__ u32 pk2(float x, float y) {      // 2xf32 -> packed bf16x2 (RNE)
    float2 t; t.x = x; t.y = y;
    __hip_bfloat162 h = __float22bfloat162_rn(t);
    return *(u32*)&h;
}

#define GLOBAL_AS __attribute__((address_space(1)))
#define LDS_AS    __attribute__((address_space(3)))
__device__ __forceinline__ void async_copy16(void* lds, const void* g) {
    __builtin_amdgcn_global_load_lds((const GLOBAL_AS u32*)g, (LDS_AS u32*)lds, 16, 0, 0);
}

// ---------------------------------------------------------------------------
// Merged projection GEMM.  BM=BN=128, BK=32, 256 threads (4 waves),
// wave tile 64x64 (acc[4][4]).  BOTH operands bf16 via global_load_lds.
// 2-phase double-buffered K-loop (T3 minimal recipe): prefetch tile kt+1
// into buf^1 BEFORE computing tile kt, one __syncthreads() per K-step at the
// bottom (its implicit vmcnt(0) drain then overlaps with ds_read+MFMA
// instead of exposing full load latency — previous rev was latency-bound:
// MfmaUtil 17.9 / VALUBusy 18.9 / HBM 20%, all low).
//   blockIdx.y < 5 : C = q_bf @ Wcat1^T + bcat1 (N=576; cols<512 -> q_ws bf16,
//                    512<=cols<576 -> offlog f32; frags >=576 skipped)
//   blockIdx.y >= 5: C = kv_bf @ Wcat2^T + bcat2 (N=1024 -> kv_ws bf16)
// ---------------------------------------------------------------------------
__global__ __launch_bounds__(256) void proj_gemm(
    const u16* __restrict__ q_bf, const u16* __restrict__ kv_bf,
    const u16* __restrict__ Wcat1, const u16* __restrict__ Wcat2,
    const float* __restrict__ bcat1, const float* __restrict__ bcat2,
    u16* __restrict__ q_ws, float* __restrict__ offlog,
    u16* __restrict__ kv_ws)
{
    constexpr int BM = 128, BK = 32;
    __shared__ u16 sA[2][BM * BK];
    __shared__ u16 sB[2][BM * BK];

    const int tid  = threadIdx.x;
    const int wave = tid >> 6;
    const int lane = tid & 63;
    const int m0 = blockIdx.x * BM;
    const bool is_q = blockIdx.y < 5;
    const int n0 = (is_q ? blockIdx.y : blockIdx.y - 5) * BM;
    const int Ncur = is_q ? 576 : 1024;
    const u16* __restrict__ A    = is_q ? q_bf : kv_bf;
    const u16* __restrict__ Wt   = is_q ? Wcat1 : Wcat2;
    const float* __restrict__ bias = is_q ? bcat1 : bcat2;

    const int wrow = 64 * (wave >> 1);
    const int wcol = 64 * (wave & 1);

    f32x4 acc[4][4] = {};
    const int lr = lane & 15;
    const int kg = lane >> 4;

    // per-lane staging addresses (invariant except k0)
    const int cA = wave * 64 + lane;            // group base (i=0 half)
    const size_t arow0 = (size_t)(m0 + (cA >> 2)) * DM + ((cA & 3) << 3);
    const int cA2 = (4 + wave) * 64 + lane;     // i=1 half
    const size_t arow1 = (size_t)(m0 + (cA2 >> 2)) * DM + ((cA2 & 3) << 3);
    const size_t brow0 = (size_t)(n0 + (cA >> 2)) * DM + ((cA & 3) << 3);
    const size_t brow1 = (size_t)(n0 + (cA2 >> 2)) * DM + ((cA2 & 3) << 3);
    const int ldsA0 = wave * 512, ldsA1 = (4 + wave) * 512;

    // prologue: stage tile 0 into buf 0
    {
        const int k0 = 0;
        async_copy16(&sA[0][ldsA0], A + arow0 + k0);
        async_copy16(&sA[0][ldsA1], A + arow1 + k0);
        async_copy16(&sB[0][ldsA0], Wt + brow0 + k0);
        async_copy16(&sB[0][ldsA1], Wt + brow1 + k0);
    }
    __syncthreads();

    int cur = 0;
    for (int kt = 0; kt < 16; ++kt) {
        // prefetch next tile into the other buffer (loads stay in flight
        // across the ds_read+MFMA below; drained by the bottom barrier)
        if (kt < 15) {
            const int k0 = (kt + 1) << 5;
            async_copy16(&sA[cur ^ 1][ldsA0], A + arow0 + k0);
            async_copy16(&sA[cur ^ 1][ldsA1], A + arow1 + k0);
            async_copy16(&sB[cur ^ 1][ldsA0], Wt + brow0 + k0);
            async_copy16(&sB[cur ^ 1][ldsA1], Wt + brow1 + k0);
        }

        const u16* __restrict__ cAp = sA[cur];
        const u16* __restrict__ cBp = sB[cur];
        frag_ab af[4], bfr[4];
#pragma unroll
        for (int i = 0; i < 4; ++i)
            af[i] = *(const frag_ab*)&cAp[(wrow + i * 16 + lr) * 32 + kg * 8];
#pragma unroll
        for (int j = 0; j < 4; ++j)
            bfr[j] = *(const frag_ab*)&cBp[(wcol + j * 16 + lr) * 32 + kg * 8];
#pragma unroll
        for (int i = 0; i < 4; ++i)
#pragma unroll
            for (int j = 0; j < 4; ++j)
                acc[i][j] = __builtin_amdgcn_mfma_f32_16x16x32_bf16(
                    af[i], bfr[j], acc[i][j], 0, 0, 0);

        if (kt < 15) __syncthreads();   // drains vmcnt(0): next buffer ready
        cur ^= 1;
    }

    const int crow0 = (lane >> 4) * 4;
#pragma unroll
    for (int i = 0; i < 4; ++i) {
#pragma unroll
        for (int j = 0; j < 4; ++j) {
            const int colbase = n0 + wcol + j * 16;
            if (colbase >= Ncur) continue;        // wave-uniform tail skip
            const int col = colbase + lr;
            const float bv = bias[col];
#pragma unroll
            for (int r = 0; r < 4; ++r) {
                const int row = m0 + wrow + i * 16 + crow0 + r;
                const float val = acc[i][j][r] + bv;
                if (!is_q)
                    kv_ws[(size_t)row * 1024 + col] = f2b(val);
                else if (colbase < 512)
                    q_ws[(size_t)row * 512 + col] = f2b(val);
                else
                    offlog[(size_t)row * 64 + (col - 512)] = val;
            }
        }
    }
}

// ---------------------------------------------------------------------------
// Output GEMM: C(f32) = A(bf16, Mx512) @ Wob^T + bo.  Same 2-phase
// double-buffered structure as proj_gemm.
// ---------------------------------------------------------------------------
__global__ __launch_bounds__(256) void out_gemm(
    const u16* __restrict__ A, const u16* __restrict__ Wt,
    const float* __restrict__ bias, float* __restrict__ C)
{
    constexpr int BM = 128, BK = 32;
    __shared__ u16 sA[2][BM * BK];
    __shared__ u16 sB[2][BM * BK];

    const int tid  = threadIdx.x;
    const int wave = tid >> 6;
    const int lane = tid & 63;
    const int m0 = blockIdx.x * BM;
    const int n0 = blockIdx.y * BM;

    const int wrow = 64 * (wave >> 1);
    const int wcol = 64 * (wave & 1);

    f32x4 acc[4][4] = {};
    const int lr = lane & 15;
    const int kg = lane >> 4;

    const int cA = wave * 64 + lane;
    const size_t arow0 = (size_t)(m0 + (cA >> 2)) * DM + ((cA & 3) << 3);
    const int cA2 = (4 + wave) * 64 + lane;
    const size_t arow1 = (size_t)(m0 + (cA2 >> 2)) * DM + ((cA2 & 3) << 3);
    const size_t brow0 = (size_t)(n0 + (cA >> 2)) * DM + ((cA & 3) << 3);
    const size_t brow1 = (size_t)(n0 + (cA2 >> 2)) * DM + ((cA2 & 3) << 3);
    const int ldsA0 = wave * 512, ldsA1 = (4 + wave) * 512;

    {
        async_copy16(&sA[0][ldsA0], A + arow0);
        async_copy16(&sA[0][ldsA1], A + arow1);
        async_copy16(&sB[0][ldsA0], Wt + brow0);
        async_copy16(&sB[0][ldsA1], Wt + brow1);
    }
    __syncthreads();

    int cur = 0;
    for (int kt = 0; kt < 16; ++kt) {
        if (kt < 15) {
            const int k0 = (kt + 1) << 5;
            async_copy16(&sA[cur ^ 1][ldsA0], A + arow0 + k0);
            async_copy16(&sA[cur ^ 1][ldsA1], A + arow1 + k0);
            async_copy16(&sB[cur ^ 1][ldsA0], Wt + brow0 + k0);
            async_copy16(&sB[cur ^ 1][ldsA1], Wt + brow1 + k0);
        }

        const u16* __restrict__ cAp = sA[cur];
        const u16* __restrict__ cBp = sB[cur];
        frag_ab af[4], bfr[4];
#pragma unroll
        for (int i = 0; i < 4; ++i)
            af[i] = *(const frag_ab*)&cAp[(wrow + i * 16 + lr) * 32 + kg * 8];
#pragma unroll
        for (int j = 0; j < 4; ++j)
            bfr[j] = *(const frag_ab*)&cBp[(wcol + j * 16 + lr) * 32 + kg * 8];
#pragma unroll
        for (int i = 0; i < 4; ++i)
#pragma unroll
            for (int j = 0; j < 4; ++j)
                acc[i][j] = __builtin_amdgcn_mfma_f32_16x16x32_bf16(
                    af[i], bfr[j], acc[i][j], 0, 0, 0);

        if (kt < 15) __syncthreads();
        cur ^= 1;
    }

    const int crow0 = (lane >> 4) * 4;
#pragma unroll
    for (int i = 0; i < 4; ++i) {
#pragma unroll
        for (int j = 0; j < 4; ++j) {
            const int col = n0 + wcol + j * 16 + lr;
            const float bv = bias[col];
#pragma unroll
            for (int r = 0; r < 4; ++r) {
                const int row = m0 + wrow + i * 16 + crow0 + r;
                C[(size_t)row * 512 + col] = acc[i][j][r] + bv;
            }
        }
    }
}

// ---------------------------------------------------------------------------
// Weight/bias prep + input pre-cast (fp32 -> bf16), one launch.
//   Wcat1 = [Wq; Woff; Wa] (576x512, alloc 768)   bcat1 = [bq; boff; ba]
//   Wcat2 = [Wk; Wv]       (1024x512)             bcat2 = [bk; bv]
//   Wob   = Wo
//   q_bf / kv_bf = bf16 casts of q_in / kv_in (8 floats -> ushort8 per thread)
// ---------------------------------------------------------------------------
__global__ __launch_bounds__(256) void prep_weights(
    const float* __restrict__ Wq, const float* __restrict__ Woff,
    const float* __restrict__ Wa, const float* __restrict__ Wk,
    const float* __restrict__ Wv, const float* __restrict__ Wo,
    const float* __restrict__ bq, const float* __restrict__ boff,
    const float* __restrict__ ba, const float* __restrict__ bk,
    const float* __restrict__ bv,
    const float* __restrict__ q_in, const float* __restrict__ kv_in,
    u16* __restrict__ Wcat1, u16* __restrict__ Wcat2, u16* __restrict__ Wob,
    float* __restrict__ bcat1, float* __restrict__ bcat2,
    u16* __restrict__ q_bf, u16* __restrict__ kv_bf, int n8)
{
    const int W4  = 65536;   // 512*512/4
    const int W4s = 4096;    // 32*512/4
    const int WEND = 4 * W4 + 2 * W4s;   // 270336
    const int BEND = WEND + 2048;        // bias section (padded)
    int tid = blockIdx.x * 256 + threadIdx.x;
    if (tid < WEND) {
        const float* src; u16* dst; int off;
        int t = tid;
        if (t < W4)                    { src = Wq;    dst = Wcat1;           off = t; }
        else if ((t -= W4) < W4s)      { src = Woff;  dst = Wcat1 + 262144;  off = t; }
        else if ((t -= W4s) < W4s)     { src = Wa;    dst = Wcat1 + 278528;  off = t; }
        else if ((t -= W4s) < W4)      { src = Wk;    dst = Wcat2;           off = t; }
        else if ((t -= W4) < W4)       { src = Wv;    dst = Wcat2 + 262144;  off = t; }
        else                           { src = Wo;    dst = Wob;             off = t - W4; }
        float4 v = ((const float4*)src)[off];
        ushort4 o;
        o.x = f2b(v.x); o.y = f2b(v.y); o.z = f2b(v.z); o.w = f2b(v.w);
        ((ushort4*)dst)[off] = o;
    } else if (tid < BEND) {
        int j = tid - WEND;
        if (j < 576) {
            bcat1[j] = (j < 512) ? bq[j] : (j < 544 ? boff[j - 512] : ba[j - 544]);
        } else if (j < 1600) {
            int j2 = j - 576;
            bcat2[j2] = (j2 < 512) ? bk[j2] : bv[j2 - 512];
        }
    } else {
        int t = tid - BEND;              // 0 .. 2*n8-1, each handles 8 floats
        if (t < 2 * n8) {
            const float* src; u16* dst; int off;
            if (t < n8) { src = q_in;  dst = q_bf;  off = t; }
            else        { src = kv_in; dst = kv_bf; off = t - n8; }
            float4 a = ((const float4*)src)[off * 2];
            float4 b = ((const float4*)src)[off * 2 + 1];
            uint4 w;
            w.x = pk2(a.x, a.y); w.y = pk2(a.z, a.w);
            w.z = pk2(b.x, b.y); w.w = pk2(b.z, b.w);
            ((uint4*)dst)[off] = w;
        }
    }
}

// ---------------------------------------------------------------------------
// Banded deformable attention. One wave per (b, h, 16-query block).
// k|v fused buffer: row stride 1024, k at cols 0..511, v at 512..1023.
// ---------------------------------------------------------------------------
__global__ __launch_bounds__(256) void deform_attn_band(
    const u16* __restrict__ q, const u16* __restrict__ kv,
    const float* __restrict__ offlog, u16* __restrict__ out, int B, int L)
{
    __shared__ u16  sVt[4][64 * 40];
    __shared__ float sS[4][16 * 36];
    __shared__ float sW[4][16 * 36];

    const int wave = threadIdx.x >> 6;
    const int lane = threadIdx.x & 63;
    const int gw = blockIdx.x * 4 + wave;     // over B*NH*(L/16)
    const int nlb = L >> 4;
    const int lblk = gw % nlb;
    const int bh = gw / nlb;
    const int h = bh % NH;
    const int b = bh / NH;
    const int l0 = lblk << 4;

    u16*  __restrict__ vt = sVt[wave];
    float* __restrict__ Ss = sS[wave];
    float* __restrict__ Ws = sW[wave];

    const size_t brow = (size_t)b * L;
    const int headoff = h * DD;

    const int l_loc = lane >> 2, p = lane & 3;
    const size_t obase = (brow + l0 + l_loc) * 64 + h * 4 + p;
    const float offv  = offlog[obase];
    const float logit = offlog[obase + 32];

    const int fr = lane & 15, kg = lane >> 4;

    const u16* qrow = q + (brow + l0 + fr) * DM + headoff;
    frag_ab qf0 = *(const frag_ab*)(qrow + kg * 8);
    frag_ab qf1 = *(const frag_ab*)(qrow + kg * 8 + 32);

    frag_ab kf[2][2];
#pragma unroll
    for (int jf = 0; jf < 2; ++jf) {
        int rr = l0 - 8 + jf * 16 + fr;
        rr = min(max(rr, 0), L - 1);
        const u16* krow = kv + (brow + rr) * 1024 + headoff;
        kf[jf][0] = *(const frag_ab*)(krow + kg * 8);
        kf[jf][1] = *(const frag_ab*)(krow + kg * 8 + 32);
    }

    const int vr = lane & 31, vd0 = (lane >> 5) * 32;
    int vrr = min(max(l0 - 8 + vr, 0), L - 1);
    const u16* vrow = kv + (brow + vrr) * 1024 + 512 + headoff + vd0;
    frag_ab vl[4];
#pragma unroll
    for (int i = 0; i < 4; ++i)
        vl[i] = *(const frag_ab*)(vrow + i * 8);

    f32x4 accS[2] = {};
#pragma unroll
    for (int jf = 0; jf < 2; ++jf) {
        accS[jf] = __builtin_amdgcn_mfma_f32_16x16x32_bf16(qf0, kf[jf][0], accS[jf], 0, 0, 0);
        accS[jf] = __builtin_amdgcn_mfma_f32_16x16x32_bf16(qf1, kf[jf][1], accS[jf], 0, 0, 0);
    }

#pragma unroll
    for (int i = 0; i < 4; ++i)
#pragma unroll
        for (int j = 0; j < 8; ++j)
            vt[(vd0 + i * 8 + j) * 40 + vr] = (u16)vl[i][j];

#pragma unroll
    for (int jf = 0; jf < 2; ++jf)
#pragma unroll
        for (int r = 0; r < 4; ++r)
            Ss[(kg * 4 + r) * 36 + jf * 16 + fr] = accS[jf][r];

#pragma unroll
    for (int i = 0; i < 9; ++i)
        Ws[lane + 64 * i] = 0.f;

    __syncthreads();

    float pos = fminf(fmaxf((float)(l0 + l_loc) + offv, 0.f), (float)(L - 1));
    float ff = floorf(pos);
    int i0 = (int)ff;
    float fw = pos - ff;
    int c0 = i0 - (l0 - 8);
    c0 = min(max(c0, 0), 30);
    float S0 = Ss[l_loc * 36 + c0];
    float S1 = Ss[l_loc * 36 + c0 + 1];
    float t = (S0 + fw * (S1 - S0)) * 0.125f + logit;
    float m1 = fmaxf(t, __shfl_xor(t, 1));
    float mx = fmaxf(m1, __shfl_xor(m1, 2));
    float e = __expf(t - mx);
    float s1 = e + __shfl_xor(e, 1);
    float ssum = s1 + __shfl_xor(s1, 2);
    float wgt = e * __builtin_amdgcn_rcpf(ssum);
    atomicAdd(&Ws[l_loc * 36 + c0], (1.f - fw) * wgt);
    atomicAdd(&Ws[l_loc * 36 + c0 + 1], fw * wgt);

    __syncthreads();

    float4 w0 = *(const float4*)&Ws[fr * 36 + kg * 8];
    float4 w1 = *(const float4*)&Ws[fr * 36 + kg * 8 + 4];
    frag_ab wf;
    wf[0] = (short)f2b(w0.x); wf[1] = (short)f2b(w0.y);
    wf[2] = (short)f2b(w0.z); wf[3] = (short)f2b(w0.w);
    wf[4] = (short)f2b(w1.x); wf[5] = (short)f2b(w1.y);
    wf[6] = (short)f2b(w1.z); wf[7] = (short)f2b(w1.w);

#pragma unroll
    for (int md = 0; md < 4; ++md) {
        frag_ab af = *(const frag_ab*)&vt[(md * 16 + fr) * 40 + kg * 8];
        f32x4 o = {};
        o = __builtin_amdgcn_mfma_f32_16x16x32_bf16(af, wf, o, 0, 0, 0);
        ushort4 pk;
        pk.x = f2b(o[0]); pk.y = f2b(o[1]); pk.z = f2b(o[2]); pk.w = f2b(o[3]);
        *(ushort4*)&out[(brow + l0 + fr) * DM + headoff + md * 16 + kg * 4] = pk;
    }
}

// ---------------------------------------------------------------------------
extern "C" void kernel_launch(void* const* d_in, const int* in_sizes, int n_in,
                              void* d_out, int out_size, void* d_ws, size_t ws_size,
                              hipStream_t stream) {
    const float* q_in  = (const float*)d_in[0];
    const float* kv_in = (const float*)d_in[1];
    const float* Wq = (const float*)d_in[2];  const float* bq = (const float*)d_in[3];
    const float* Wk = (const float*)d_in[4];  const float* bk = (const float*)d_in[5];
    const float* Wv = (const float*)d_in[6];  const float* bv = (const float*)d_in[7];
    const float* Woff=(const float*)d_in[8];  const float* boff=(const float*)d_in[9];
    const float* Wa = (const float*)d_in[10]; const float* ba = (const float*)d_in[11];
    const float* Wo = (const float*)d_in[12]; const float* bo = (const float*)d_in[13];

    const int M = in_sizes[0] / DM;     // B*L = 16384
    const int L = 4096;
    const int B = M / L;

    char* p = (char*)d_ws;
    u16* attn_o = (u16*)p;               p += (size_t)M * DM * 2;     // attention output
    u16* Wcat1  = (u16*)p;               p += (size_t)768 * DM * 2;   // 640 used; pad for OOB staging
    u16* Wcat2  = (u16*)p;               p += (size_t)1024 * DM * 2;
    u16* Wob    = (u16*)p;               p += (size_t)DM * DM * 2;
    float* bcat1= (float*)p;             p += 640 * 4;
    float* bcat2= (float*)p;             p += 1024 * 4;
    u16* q_ws   = (u16*)p;               p += (size_t)M * DM * 2;
    u16* kv_ws  = (u16*)p;               p += (size_t)M * 1024 * 2;   // k|v fused
    float* offlog = (float*)p;           p += (size_t)M * 64 * 4;

    // bf16 input casts — alias dead regions (same-stream serialization):
    //   q_bf  lives prep->proj; attn_o is only written later by deform_attn_band
    //   kv_bf lives prep->proj; d_out is only written later by out_gemm (fully)
    u16* q_bf  = attn_o;
    u16* kv_bf = (u16*)d_out;

    const int n8 = M * DM / 8;          // 8 floats per cast thread
    const int prep_threads = 4 * 65536 + 2 * 4096 + 2048 + 2 * n8;
    hipLaunchKernelGGL(prep_weights, dim3((prep_threads + 255) / 256), dim3(256), 0, stream,
                       Wq, Woff, Wa, Wk, Wv, Wo, bq, boff, ba, bk, bv,
                       q_in, kv_in,
                       Wcat1, Wcat2, Wob, bcat1, bcat2, q_bf, kv_bf, n8);

    // merged projections (all-bf16 async staging): y<5 -> q/off/a, y>=5 -> k|v
    hipLaunchKernelGGL(proj_gemm, dim3(M / 128, 13), dim3(256), 0, stream,
                       q_bf, kv_bf, Wcat1, Wcat2, bcat1, bcat2,
                       q_ws, offlog, kv_ws);

    // banded attention: 1 wave per (b,h,16 queries)
    int nwaves = B * NH * (L / 16);
    hipLaunchKernelGGL(deform_attn_band, dim3(nwaves / 4), dim3(256), 0, stream,
                       q_ws, kv_ws, offlog, attn_o, B, L);

    // output projection -> fp32 d_out
    hipLaunchKernelGGL(out_gemm, dim3(M / 128, 4), dim3(256), 0, stream,
                       attn_o, Wob, bo, (float*)d_out);
}

// Round 3
// 203.332 us; speedup vs baseline: 1.0641x; 1.0641x over previous
//
#include <hip/hip_runtime.h>
#include <hip/hip_bf16.h>
#include <math.h>

#define NH 8
#define NP 4
#define DD 64
#define DM 512

typedef unsigned short u16;
typedef unsigned int u32;

using frag_ab = __attribute__((ext_vector_type(8))) short;  // 8 bf16 (4 VGPRs)
using f32x4   = __attribute__((ext_vector_type(4))) float;  // 4 fp32 acc

__device__ __forceinline__ u16 f2b(float f) {               // fp32 -> bf16 (RNE)
    u32 u = __float_as_uint(f);
    u32 r = (u + 0x7FFFu + ((u >> 16) & 1u)) >> 16;
    return (u16)r;
}
__device__ __forceinline__ u32 pk2(float x, float y) {      // 2xf32 -> packed bf16x2 (RNE)
    float2 t; t.x = x; t.y = y;
    __hip_bfloat162 h = __float22bfloat162_rn(t);
    return *(u32*)&h;
}

#define GLOBAL_AS __attribute__((address_space(1)))
#define LDS_AS    __attribute__((address_space(3)))
__device__ __forceinline__ void async_copy16(void* lds, const void* g) {
    __builtin_amdgcn_global_load_lds((const GLOBAL_AS u32*)g, (LDS_AS u32*)lds, 16, 0, 0);
}

// counted-vmcnt barrier: tile issued one step ago is complete in LDS for ALL
// waves; the newest 4 loads (next tile's prefetch) stay in flight across the
// barrier (T4 — never drain vmcnt to 0 in the main loop).
#define VMW4_BARRIER() do {                                   \
    asm volatile("s_waitcnt vmcnt(4)" ::: "memory");          \
    __builtin_amdgcn_s_barrier();                             \
    __builtin_amdgcn_sched_barrier(0); } while (0)
#define VMW0_BARRIER() do {                                   \
    asm volatile("s_waitcnt vmcnt(0)" ::: "memory");          \
    __builtin_amdgcn_s_barrier();                             \
    __builtin_amdgcn_sched_barrier(0); } while (0)

// ds_read the wave's fragments, retire them (lgkmcnt(0)+barrier => buffer may
// be overwritten by the next prefetch), then MFMA.
__device__ __forceinline__ void compute_phase(
    const u16* __restrict__ sa, const u16* __restrict__ sb,
    int wrow, int wcol, int lr, int kg, f32x4 (&acc)[4][4])
{
    frag_ab af[4], bfr[4];
#pragma unroll
    for (int i = 0; i < 4; ++i)
        af[i] = *(const frag_ab*)&sa[(wrow + i * 16 + lr) * 32 + kg * 8];
#pragma unroll
    for (int j = 0; j < 4; ++j)
        bfr[j] = *(const frag_ab*)&sb[(wcol + j * 16 + lr) * 32 + kg * 8];
    asm volatile("s_waitcnt lgkmcnt(0)" ::: "memory");
    __builtin_amdgcn_s_barrier();
    __builtin_amdgcn_sched_barrier(0);
#pragma unroll
    for (int i = 0; i < 4; ++i)
#pragma unroll
        for (int j = 0; j < 4; ++j)
            acc[i][j] = __builtin_amdgcn_mfma_f32_16x16x32_bf16(
                af[i], bfr[j], acc[i][j], 0, 0, 0);
}

// ---------------------------------------------------------------------------
// Merged projection GEMM.  BM=BN=128, BK=32, 256 threads (4 waves),
// wave tile 64x64 (acc[4][4]).  BOTH operands bf16 via global_load_lds.
// Counted-vmcnt double-buffered pipeline (T4): prefetch tile t+1 is issued a
// FULL K-step before use and is never drained by the barrier (vmcnt(4), not
// 0).  Static LDS buffers (unroll-by-2) — no runtime buffer indexing.
//   blockIdx.y < 5 : C = q_bf @ Wcat1^T + bcat1 (N=576; cols<512 -> q_ws bf16,
//                    512<=cols<576 -> offlog f32; frags >=576 skipped)
//   blockIdx.y >= 5: C = kv_bf @ Wcat2^T + bcat2 (N=1024 -> kv_ws bf16)
// ---------------------------------------------------------------------------
__global__ __launch_bounds__(256) void proj_gemm(
    const u16* __restrict__ q_bf, const u16* __restrict__ kv_bf,
    const u16* __restrict__ Wcat1, const u16* __restrict__ Wcat2,
    const float* __restrict__ bcat1, const float* __restrict__ bcat2,
    u16* __restrict__ q_ws, float* __restrict__ offlog,
    u16* __restrict__ kv_ws)
{
    constexpr int BM = 128, BK = 32;
    __shared__ u16 sA0[BM * BK], sA1[BM * BK];
    __shared__ u16 sB0[BM * BK], sB1[BM * BK];

    const int tid  = threadIdx.x;
    const int wave = tid >> 6;
    const int lane = tid & 63;
    const int m0 = blockIdx.x * BM;
    const bool is_q = blockIdx.y < 5;
    const int n0 = (is_q ? blockIdx.y : blockIdx.y - 5) * BM;
    const int Ncur = is_q ? 576 : 1024;
    const u16* __restrict__ A    = is_q ? q_bf : kv_bf;
    const u16* __restrict__ Wt   = is_q ? Wcat1 : Wcat2;
    const float* __restrict__ bias = is_q ? bcat1 : bcat2;

    const int wrow = 64 * (wave >> 1);
    const int wcol = 64 * (wave & 1);

    f32x4 acc[4][4] = {};
    const int lr = lane & 15;
    const int kg = lane >> 4;

    // hoist bias loads (oldest vm ops -> retire before the vmcnt(4) pipeline;
    // keeps the in-loop vmcnt FIFO count exact).  Alloc pads make all 4 loads
    // in-bounds: bcat1 has 640 floats, bcat2 1024.
    float bv4[4];
#pragma unroll
    for (int j = 0; j < 4; ++j)
        bv4[j] = bias[n0 + wcol + j * 16 + lr];

    // per-lane staging addresses (invariant except k0)
    const int cA = wave * 64 + lane;            // group base (first half)
    const size_t arow0 = (size_t)(m0 + (cA >> 2)) * DM + ((cA & 3) << 3);
    const int cA2 = (4 + wave) * 64 + lane;     // second half
    const size_t arow1 = (size_t)(m0 + (cA2 >> 2)) * DM + ((cA2 & 3) << 3);
    const size_t brow0 = (size_t)(n0 + (cA >> 2)) * DM + ((cA & 3) << 3);
    const size_t brow1 = (size_t)(n0 + (cA2 >> 2)) * DM + ((cA2 & 3) << 3);
    const int ldsA0 = wave * 512, ldsA1 = (4 + wave) * 512;

    auto stage = [&](u16* sa, u16* sb, int k0) {   // 4 loads per wave per tile
        async_copy16(&sa[ldsA0], A + arow0 + k0);
        async_copy16(&sa[ldsA1], A + arow1 + k0);
        async_copy16(&sb[ldsA0], Wt + brow0 + k0);
        async_copy16(&sb[ldsA1], Wt + brow1 + k0);
    };

    stage(sA0, sB0, 0);                          // prologue: tile 0 in flight

    for (int ktt = 0; ktt < 8; ++ktt) {
        // ---- phase A: prefetch tile 2ktt+1 -> buf1, compute tile 2ktt ----
        stage(sA1, sB1, (2 * ktt + 1) << 5);
        VMW4_BARRIER();                          // tile 2ktt ready; t+1 in flight
        compute_phase(sA0, sB0, wrow, wcol, lr, kg, acc);
        // ---- phase B: prefetch tile 2ktt+2 -> buf0, compute tile 2ktt+1 --
        if (ktt < 7) {
            stage(sA0, sB0, (2 * ktt + 2) << 5);
            VMW4_BARRIER();
        } else {
            VMW0_BARRIER();                      // epilogue drain (last tile)
        }
        compute_phase(sA1, sB1, wrow, wcol, lr, kg, acc);
    }

    const int crow0 = (lane >> 4) * 4;
#pragma unroll
    for (int i = 0; i < 4; ++i) {
#pragma unroll
        for (int j = 0; j < 4; ++j) {
            const int colbase = n0 + wcol + j * 16;
            if (colbase >= Ncur) continue;        // wave-uniform tail skip
            const int col = colbase + lr;
            const float bv = bv4[j];
#pragma unroll
            for (int r = 0; r < 4; ++r) {
                const int row = m0 + wrow + i * 16 + crow0 + r;
                const float val = acc[i][j][r] + bv;
                if (!is_q)
                    kv_ws[(size_t)row * 1024 + col] = f2b(val);
                else if (colbase < 512)
                    q_ws[(size_t)row * 512 + col] = f2b(val);
                else
                    offlog[(size_t)row * 64 + (col - 512)] = val;
            }
        }
    }
}

// ---------------------------------------------------------------------------
// Output GEMM: C(f32) = A(bf16, Mx512) @ Wob^T + bo.  Same counted-vmcnt
// pipelined structure as proj_gemm.
// ---------------------------------------------------------------------------
__global__ __launch_bounds__(256) void out_gemm(
    const u16* __restrict__ A, const u16* __restrict__ Wt,
    const float* __restrict__ bias, float* __restrict__ C)
{
    constexpr int BM = 128, BK = 32;
    __shared__ u16 sA0[BM * BK], sA1[BM * BK];
    __shared__ u16 sB0[BM * BK], sB1[BM * BK];

    const int tid  = threadIdx.x;
    const int wave = tid >> 6;
    const int lane = tid & 63;
    const int m0 = blockIdx.x * BM;
    const int n0 = blockIdx.y * BM;

    const int wrow = 64 * (wave >> 1);
    const int wcol = 64 * (wave & 1);

    f32x4 acc[4][4] = {};
    const int lr = lane & 15;
    const int kg = lane >> 4;

    float bv4[4];
#pragma unroll
    for (int j = 0; j < 4; ++j)
        bv4[j] = bias[n0 + wcol + j * 16 + lr];  // col <= 511, in-bounds

    const int cA = wave * 64 + lane;
    const size_t arow0 = (size_t)(m0 + (cA >> 2)) * DM + ((cA & 3) << 3);
    const int cA2 = (4 + wave) * 64 + lane;
    const size_t arow1 = (size_t)(m0 + (cA2 >> 2)) * DM + ((cA2 & 3) << 3);
    const size_t brow0 = (size_t)(n0 + (cA >> 2)) * DM + ((cA & 3) << 3);
    const size_t brow1 = (size_t)(n0 + (cA2 >> 2)) * DM + ((cA2 & 3) << 3);
    const int ldsA0 = wave * 512, ldsA1 = (4 + wave) * 512;

    auto stage = [&](u16* sa, u16* sb, int k0) {
        async_copy16(&sa[ldsA0], A + arow0 + k0);
        async_copy16(&sa[ldsA1], A + arow1 + k0);
        async_copy16(&sb[ldsA0], Wt + brow0 + k0);
        async_copy16(&sb[ldsA1], Wt + brow1 + k0);
    };

    stage(sA0, sB0, 0);

    for (int ktt = 0; ktt < 8; ++ktt) {
        stage(sA1, sB1, (2 * ktt + 1) << 5);
        VMW4_BARRIER();
        compute_phase(sA0, sB0, wrow, wcol, lr, kg, acc);
        if (ktt < 7) {
            stage(sA0, sB0, (2 * ktt + 2) << 5);
            VMW4_BARRIER();
        } else {
            VMW0_BARRIER();
        }
        compute_phase(sA1, sB1, wrow, wcol, lr, kg, acc);
    }

    const int crow0 = (lane >> 4) * 4;
#pragma unroll
    for (int i = 0; i < 4; ++i) {
#pragma unroll
        for (int j = 0; j < 4; ++j) {
            const int col = n0 + wcol + j * 16 + lr;
            const float bv = bv4[j];
#pragma unroll
            for (int r = 0; r < 4; ++r) {
                const int row = m0 + wrow + i * 16 + crow0 + r;
                C[(size_t)row * 512 + col] = acc[i][j][r] + bv;
            }
        }
    }
}

// ---------------------------------------------------------------------------
// Weight/bias prep + input pre-cast (fp32 -> bf16), one launch.
//   Wcat1 = [Wq; Woff; Wa] (576x512, alloc 768)   bcat1 = [bq; boff; ba]
//   Wcat2 = [Wk; Wv]       (1024x512)             bcat2 = [bk; bv]
//   Wob   = Wo
//   q_bf / kv_bf = bf16 casts of q_in / kv_in (8 floats -> ushort8 per thread)
// ---------------------------------------------------------------------------
__global__ __launch_bounds__(256) void prep_weights(
    const float* __restrict__ Wq, const float* __restrict__ Woff,
    const float* __restrict__ Wa, const float* __restrict__ Wk,
    const float* __restrict__ Wv, const float* __restrict__ Wo,
    const float* __restrict__ bq, const float* __restrict__ boff,
    const float* __restrict__ ba, const float* __restrict__ bk,
    const float* __restrict__ bv,
    const float* __restrict__ q_in, const float* __restrict__ kv_in,
    u16* __restrict__ Wcat1, u16* __restrict__ Wcat2, u16* __restrict__ Wob,
    float* __restrict__ bcat1, float* __restrict__ bcat2,
    u16* __restrict__ q_bf, u16* __restrict__ kv_bf, int n8)
{
    const int W4  = 65536;   // 512*512/4
    const int W4s = 4096;    // 32*512/4
    const int WEND = 4 * W4 + 2 * W4s;   // 270336
    const int BEND = WEND + 2048;        // bias section (padded)
    int tid = blockIdx.x * 256 + threadIdx.x;
    if (tid < WEND) {
        const float* src; u16* dst; int off;
        int t = tid;
        if (t < W4)                    { src = Wq;    dst = Wcat1;           off = t; }
        else if ((t -= W4) < W4s)      { src = Woff;  dst = Wcat1 + 262144;  off = t; }
        else if ((t -= W4s) < W4s)     { src = Wa;    dst = Wcat1 + 278528;  off = t; }
        else if ((t -= W4s) < W4)      { src = Wk;    dst = Wcat2;           off = t; }
        else if ((t -= W4) < W4)       { src = Wv;    dst = Wcat2 + 262144;  off = t; }
        else                           { src = Wo;    dst = Wob;             off = t - W4; }
        float4 v = ((const float4*)src)[off];
        ushort4 o;
        o.x = f2b(v.x); o.y = f2b(v.y); o.z = f2b(v.z); o.w = f2b(v.w);
        ((ushort4*)dst)[off] = o;
    } else if (tid < BEND) {
        int j = tid - WEND;
        if (j < 576) {
            bcat1[j] = (j < 512) ? bq[j] : (j < 544 ? boff[j - 512] : ba[j - 544]);
        } else if (j < 1600) {
            int j2 = j - 576;
            bcat2[j2] = (j2 < 512) ? bk[j2] : bv[j2 - 512];
        }
    } else {
        int t = tid - BEND;              // 0 .. 2*n8-1, each handles 8 floats
        if (t < 2 * n8) {
            const float* src; u16* dst; int off;
            if (t < n8) { src = q_in;  dst = q_bf;  off = t; }
            else        { src = kv_in; dst = kv_bf; off = t - n8; }
            float4 a = ((const float4*)src)[off * 2];
            float4 b = ((const float4*)src)[off * 2 + 1];
            uint4 w;
            w.x = pk2(a.x, a.y); w.y = pk2(a.z, a.w);
            w.z = pk2(b.x, b.y); w.w = pk2(b.z, b.w);
            ((uint4*)dst)[off] = w;
        }
    }
}

// ---------------------------------------------------------------------------
// Banded deformable attention. One wave per (b, h, 16-query block).
// k|v fused buffer: row stride 1024, k at cols 0..511, v at 512..1023.
// ---------------------------------------------------------------------------
__global__ __launch_bounds__(256) void deform_attn_band(
    const u16* __restrict__ q, const u16* __restrict__ kv,
    const float* __restrict__ offlog, u16* __restrict__ out, int B, int L)
{
    __shared__ u16  sVt[4][64 * 40];
    __shared__ float sS[4][16 * 36];
    __shared__ float sW[4][16 * 36];

    const int wave = threadIdx.x >> 6;
    const int lane = threadIdx.x & 63;
    const int gw = blockIdx.x * 4 + wave;     // over B*NH*(L/16)
    const int nlb = L >> 4;
    const int lblk = gw % nlb;
    const int bh = gw / nlb;
    const int h = bh % NH;
    const int b = bh / NH;
    const int l0 = lblk << 4;

    u16*  __restrict__ vt = sVt[wave];
    float* __restrict__ Ss = sS[wave];
    float* __restrict__ Ws = sW[wave];

    const size_t brow = (size_t)b * L;
    const int headoff = h * DD;

    const int l_loc = lane >> 2, p = lane & 3;
    const size_t obase = (brow + l0 + l_loc) * 64 + h * 4 + p;
    const float offv  = offlog[obase];
    const float logit = offlog[obase + 32];

    const int fr = lane & 15, kg = lane >> 4;

    const u16* qrow = q + (brow + l0 + fr) * DM + headoff;
    frag_ab qf0 = *(const frag_ab*)(qrow + kg * 8);
    frag_ab qf1 = *(const frag_ab*)(qrow + kg * 8 + 32);

    frag_ab kf[2][2];
#pragma unroll
    for (int jf = 0; jf < 2; ++jf) {
        int rr = l0 - 8 + jf * 16 + fr;
        rr = min(max(rr, 0), L - 1);
        const u16* krow = kv + (brow + rr) * 1024 + headoff;
        kf[jf][0] = *(const frag_ab*)(krow + kg * 8);
        kf[jf][1] = *(const frag_ab*)(krow + kg * 8 + 32);
    }

    const int vr = lane & 31, vd0 = (lane >> 5) * 32;
    int vrr = min(max(l0 - 8 + vr, 0), L - 1);
    const u16* vrow = kv + (brow + vrr) * 1024 + 512 + headoff + vd0;
    frag_ab vl[4];
#pragma unroll
    for (int i = 0; i < 4; ++i)
        vl[i] = *(const frag_ab*)(vrow + i * 8);

    f32x4 accS[2] = {};
#pragma unroll
    for (int jf = 0; jf < 2; ++jf) {
        accS[jf] = __builtin_amdgcn_mfma_f32_16x16x32_bf16(qf0, kf[jf][0], accS[jf], 0, 0, 0);
        accS[jf] = __builtin_amdgcn_mfma_f32_16x16x32_bf16(qf1, kf[jf][1], accS[jf], 0, 0, 0);
    }

#pragma unroll
    for (int i = 0; i < 4; ++i)
#pragma unroll
        for (int j = 0; j < 8; ++j)
            vt[(vd0 + i * 8 + j) * 40 + vr] = (u16)vl[i][j];

#pragma unroll
    for (int jf = 0; jf < 2; ++jf)
#pragma unroll
        for (int r = 0; r < 4; ++r)
            Ss[(kg * 4 + r) * 36 + jf * 16 + fr] = accS[jf][r];

#pragma unroll
    for (int i = 0; i < 9; ++i)
        Ws[lane + 64 * i] = 0.f;

    __syncthreads();

    float pos = fminf(fmaxf((float)(l0 + l_loc) + offv, 0.f), (float)(L - 1));
    float ff = floorf(pos);
    int i0 = (int)ff;
    float fw = pos - ff;
    int c0 = i0 - (l0 - 8);
    c0 = min(max(c0, 0), 30);
    float S0 = Ss[l_loc * 36 + c0];
    float S1 = Ss[l_loc * 36 + c0 + 1];
    float t = (S0 + fw * (S1 - S0)) * 0.125f + logit;
    float m1 = fmaxf(t, __shfl_xor(t, 1));
    float mx = fmaxf(m1, __shfl_xor(m1, 2));
    float e = __expf(t - mx);
    float s1 = e + __shfl_xor(e, 1);
    float ssum = s1 + __shfl_xor(s1, 2);
    float wgt = e * __builtin_amdgcn_rcpf(ssum);
    atomicAdd(&Ws[l_loc * 36 + c0], (1.f - fw) * wgt);
    atomicAdd(&Ws[l_loc * 36 + c0 + 1], fw * wgt);

    __syncthreads();

    float4 w0 = *(const float4*)&Ws[fr * 36 + kg * 8];
    float4 w1 = *(const float4*)&Ws[fr * 36 + kg * 8 + 4];
    frag_ab wf;
    wf[0] = (short)f2b(w0.x); wf[1] = (short)f2b(w0.y);
    wf[2] = (short)f2b(w0.z); wf[3] = (short)f2b(w0.w);
    wf[4] = (short)f2b(w1.x); wf[5] = (short)f2b(w1.y);
    wf[6] = (short)f2b(w1.z); wf[7] = (short)f2b(w1.w);

#pragma unroll
    for (int md = 0; md < 4; ++md) {
        frag_ab af = *(const frag_ab*)&vt[(md * 16 + fr) * 40 + kg * 8];
        f32x4 o = {};
        o = __builtin_amdgcn_mfma_f32_16x16x32_bf16(af, wf, o, 0, 0, 0);
        ushort4 pk;
        pk.x = f2b(o[0]); pk.y = f2b(o[1]); pk.z = f2b(o[2]); pk.w = f2b(o[3]);
        *(ushort4*)&out[(brow + l0 + fr) * DM + headoff + md * 16 + kg * 4] = pk;
    }
}

// ---------------------------------------------------------------------------
extern "C" void kernel_launch(void* const* d_in, const int* in_sizes, int n_in,
                              void* d_out, int out_size, void* d_ws, size_t ws_size,
                              hipStream_t stream) {
    const float* q_in  = (const float*)d_in[0];
    const float* kv_in = (const float*)d_in[1];
    const float* Wq = (const float*)d_in[2];  const float* bq = (const float*)d_in[3];
    const float* Wk = (const float*)d_in[4];  const float* bk = (const float*)d_in[5];
    const float* Wv = (const float*)d_in[6];  const float* bv = (const float*)d_in[7];
    const float* Woff=(const float*)d_in[8];  const float* boff=(const float*)d_in[9];
    const float* Wa = (const float*)d_in[10]; const float* ba = (const float*)d_in[11];
    const float* Wo = (const float*)d_in[12]; const float* bo = (const float*)d_in[13];

    const int M = in_sizes[0] / DM;     // B*L = 16384
    const int L = 4096;
    const int B = M / L;

    char* p = (char*)d_ws;
    u16* attn_o = (u16*)p;               p += (size_t)M * DM * 2;     // attention output
    u16* Wcat1  = (u16*)p;               p += (size_t)768 * DM * 2;   // 640 used; pad for OOB staging
    u16* Wcat2  = (u16*)p;               p += (size_t)1024 * DM * 2;
    u16* Wob    = (u16*)p;               p += (size_t)DM * DM * 2;
    float* bcat1= (float*)p;             p += 640 * 4;
    float* bcat2= (float*)p;             p += 1024 * 4;
    u16* q_ws   = (u16*)p;               p += (size_t)M * DM * 2;
    u16* kv_ws  = (u16*)p;               p += (size_t)M * 1024 * 2;   // k|v fused
    float* offlog = (float*)p;           p += (size_t)M * 64 * 4;

    // bf16 input casts — alias dead regions (same-stream serialization):
    //   q_bf  lives prep->proj; attn_o is only written later by deform_attn_band
    //   kv_bf lives prep->proj; d_out is only written later by out_gemm (fully)
    u16* q_bf  = attn_o;
    u16* kv_bf = (u16*)d_out;

    const int n8 = M * DM / 8;          // 8 floats per cast thread
    const int prep_threads = 4 * 65536 + 2 * 4096 + 2048 + 2 * n8;
    hipLaunchKernelGGL(prep_weights, dim3((prep_threads + 255) / 256), dim3(256), 0, stream,
                       Wq, Woff, Wa, Wk, Wv, Wo, bq, boff, ba, bk, bv,
                       q_in, kv_in,
                       Wcat1, Wcat2, Wob, bcat1, bcat2, q_bf, kv_bf, n8);

    // merged projections (all-bf16 async staging): y<5 -> q/off/a, y>=5 -> k|v
    hipLaunchKernelGGL(proj_gemm, dim3(M / 128, 13), dim3(256), 0, stream,
                       q_bf, kv_bf, Wcat1, Wcat2, bcat1, bcat2,
                       q_ws, offlog, kv_ws);

    // banded attention: 1 wave per (b,h,16 queries)
    int nwaves = B * NH * (L / 16);
    hipLaunchKernelGGL(deform_attn_band, dim3(nwaves / 4), dim3(256), 0, stream,
                       q_ws, kv_ws, offlog, attn_o, B, L);

    // output projection -> fp32 d_out
    hipLaunchKernelGGL(out_gemm, dim3(M / 128, 4), dim3(256), 0, stream,
                       attn_o, Wob, bo, (float*)d_out);
}

// Round 4
// 201.131 us; speedup vs baseline: 1.0757x; 1.0109x over previous
//
#include <hip/hip_runtime.h>
#include <hip/hip_bf16.h>
#include <math.h>

#define NH 8
#define NP 4
#define DD 64
#define DM 512

typedef unsigned short u16;
typedef unsigned int u32;

using frag_ab = __attribute__((ext_vector_type(8))) short;  // 8 bf16 (4 VGPRs)
using f32x4   = __attribute__((ext_vector_type(4))) float;  // 4 fp32 acc

__device__ __forceinline__ u16 f2b(float f) {               // fp32 -> bf16 (RNE)
    u32 u = __float_as_uint(f);
    u32 r = (u + 0x7FFFu + ((u >> 16) & 1u)) >> 16;
    return (u16)r;
}
__device__ __forceinline__ u32 pk2(float x, float y) {      // 2xf32 -> packed bf16x2 (RNE)
    float2 t; t.x = x; t.y = y;
    __hip_bfloat162 h = __float22bfloat162_rn(t);
    return *(u32*)&h;
}

#define GLOBAL_AS __attribute__((address_space(1)))
#define LDS_AS    __attribute__((address_space(3)))
__device__ __forceinline__ void async_copy16(void* lds, const void* g) {
    __builtin_amdgcn_global_load_lds((const GLOBAL_AS u32*)g, (LDS_AS u32*)lds, 16, 0, 0);
}

// counted-vmcnt barrier: tile issued one step ago is complete in LDS for ALL
// waves; the newest 4 loads (next tile's prefetch) stay in flight across the
// barrier (T4 — never drain vmcnt to 0 in the main loop).
#define VMW4_BARRIER() do {                                   \
    asm volatile("s_waitcnt vmcnt(4)" ::: "memory");          \
    __builtin_amdgcn_s_barrier();                             \
    __builtin_amdgcn_sched_barrier(0); } while (0)
#define VMW0_BARRIER() do {                                   \
    asm volatile("s_waitcnt vmcnt(0)" ::: "memory");          \
    __builtin_amdgcn_s_barrier();                             \
    __builtin_amdgcn_sched_barrier(0); } while (0)

// T2 XOR swizzle: LDS slot s (16B) of row r holds global slot s ^ ((r>>1)&3).
// gload_lds writes linearly, so the permutation is applied on the per-lane
// GLOBAL source (rule 21: both-sides-or-neither); ds_read inverts it.  With
// rows % 16 == 0 per fragment, both sides reduce to per-lane constants.
// Read pattern becomes 2-way (free, m136) instead of 8-way.
__device__ __forceinline__ void compute_phase(
    const u16* __restrict__ sa, const u16* __restrict__ sb,
    int wrow, int wcol, int lr, int kgs, f32x4 (&acc)[4][4])
{
    frag_ab af[4], bfr[4];
#pragma unroll
    for (int i = 0; i < 4; ++i)
        af[i] = *(const frag_ab*)&sa[(wrow + i * 16 + lr) * 32 + kgs];
#pragma unroll
    for (int j = 0; j < 4; ++j)
        bfr[j] = *(const frag_ab*)&sb[(wcol + j * 16 + lr) * 32 + kgs];
    asm volatile("s_waitcnt lgkmcnt(0)" ::: "memory");
    __builtin_amdgcn_s_barrier();
    __builtin_amdgcn_sched_barrier(0);
#pragma unroll
    for (int i = 0; i < 4; ++i)
#pragma unroll
        for (int j = 0; j < 4; ++j)
            acc[i][j] = __builtin_amdgcn_mfma_f32_16x16x32_bf16(
                af[i], bfr[j], acc[i][j], 0, 0, 0);
}

// ---------------------------------------------------------------------------
// Merged projection GEMM.  BM=BN=128, BK=32, 256 threads (4 waves),
// wave tile 64x64 (acc[4][4]).  BOTH operands bf16 via global_load_lds.
// Counted-vmcnt double-buffered pipeline (T4) + T2 slot swizzle.
//   blockIdx.y < 5 : C = q_bf @ Wcat1^T + bcat1 (N=576; cols<512 -> q_ws bf16,
//                    512<=cols<576 -> offlog f32; frags >=576 skipped)
//   blockIdx.y >= 5: C = kv_bf @ Wcat2^T + bcat2 (N=1024 -> kv_ws bf16)
// ---------------------------------------------------------------------------
__global__ __launch_bounds__(256) void proj_gemm(
    const u16* __restrict__ q_bf, const u16* __restrict__ kv_bf,
    const u16* __restrict__ Wcat1, const u16* __restrict__ Wcat2,
    const float* __restrict__ bcat1, const float* __restrict__ bcat2,
    u16* __restrict__ q_ws, float* __restrict__ offlog,
    u16* __restrict__ kv_ws)
{
    constexpr int BM = 128, BK = 32;
    __shared__ u16 sA0[BM * BK], sA1[BM * BK];
    __shared__ u16 sB0[BM * BK], sB1[BM * BK];

    const int tid  = threadIdx.x;
    const int wave = tid >> 6;
    const int lane = tid & 63;
    const int m0 = blockIdx.x * BM;
    const bool is_q = blockIdx.y < 5;
    const int n0 = (is_q ? blockIdx.y : blockIdx.y - 5) * BM;
    const int Ncur = is_q ? 576 : 1024;
    const u16* __restrict__ A    = is_q ? q_bf : kv_bf;
    const u16* __restrict__ Wt   = is_q ? Wcat1 : Wcat2;
    const float* __restrict__ bias = is_q ? bcat1 : bcat2;

    const int wrow = 64 * (wave >> 1);
    const int wcol = 64 * (wave & 1);

    f32x4 acc[4][4] = {};
    const int lr = lane & 15;
    const int kg = lane >> 4;
    // swizzled read slot (per-lane constant: fragment rows are 0 mod 16)
    const int kgs = ((kg ^ ((lr >> 1) & 3)) << 3);
    // swizzled staging source slot (per-lane constant: chunk row = lane>>2 + 16*grp)
    const int sgo = (((lane & 3) ^ ((lane >> 3) & 3)) << 3);

    // hoist bias loads (oldest vm ops retire before the vmcnt(4) pipeline).
    float bv4[4];
#pragma unroll
    for (int j = 0; j < 4; ++j)
        bv4[j] = bias[n0 + wcol + j * 16 + lr];

    // per-lane staging addresses (invariant except k0); source slot swizzled
    const int cA = wave * 64 + lane;            // group base (first half)
    const size_t arow0 = (size_t)(m0 + (cA >> 2)) * DM + sgo;
    const int cA2 = (4 + wave) * 64 + lane;     // second half
    const size_t arow1 = (size_t)(m0 + (cA2 >> 2)) * DM + sgo;
    const size_t brow0 = (size_t)(n0 + (cA >> 2)) * DM + sgo;
    const size_t brow1 = (size_t)(n0 + (cA2 >> 2)) * DM + sgo;
    const int ldsA0 = wave * 512, ldsA1 = (4 + wave) * 512;

    auto stage = [&](u16* sa, u16* sb, int k0) {   // 4 loads per wave per tile
        async_copy16(&sa[ldsA0], A + arow0 + k0);
        async_copy16(&sa[ldsA1], A + arow1 + k0);
        async_copy16(&sb[ldsA0], Wt + brow0 + k0);
        async_copy16(&sb[ldsA1], Wt + brow1 + k0);
    };

    stage(sA0, sB0, 0);                          // prologue: tile 0 in flight

    for (int ktt = 0; ktt < 8; ++ktt) {
        // ---- phase A: prefetch tile 2ktt+1 -> buf1, compute tile 2ktt ----
        stage(sA1, sB1, (2 * ktt + 1) << 5);
        VMW4_BARRIER();                          // tile 2ktt ready; t+1 in flight
        compute_phase(sA0, sB0, wrow, wcol, lr, kgs, acc);
        // ---- phase B: prefetch tile 2ktt+2 -> buf0, compute tile 2ktt+1 --
        if (ktt < 7) {
            stage(sA0, sB0, (2 * ktt + 2) << 5);
            VMW4_BARRIER();
        } else {
            VMW0_BARRIER();                      // epilogue drain (last tile)
        }
        compute_phase(sA1, sB1, wrow, wcol, lr, kgs, acc);
    }

    const int crow0 = (lane >> 4) * 4;
#pragma unroll
    for (int i = 0; i < 4; ++i) {
#pragma unroll
        for (int j = 0; j < 4; ++j) {
            const int colbase = n0 + wcol + j * 16;
            if (colbase >= Ncur) continue;        // wave-uniform tail skip
            const int col = colbase + lr;
            const float bv = bv4[j];
#pragma unroll
            for (int r = 0; r < 4; ++r) {
                const int row = m0 + wrow + i * 16 + crow0 + r;
                const float val = acc[i][j][r] + bv;
                if (!is_q)
                    kv_ws[(size_t)row * 1024 + col] = f2b(val);
                else if (colbase < 512)
                    q_ws[(size_t)row * 512 + col] = f2b(val);
                else
                    offlog[(size_t)row * 64 + (col - 512)] = val;
            }
        }
    }
}

// ---------------------------------------------------------------------------
// Output GEMM: C(f32) = A(bf16, Mx512) @ Wob^T + bo.  Same counted-vmcnt
// pipelined structure + T2 swizzle as proj_gemm.
// ---------------------------------------------------------------------------
__global__ __launch_bounds__(256) void out_gemm(
    const u16* __restrict__ A, const u16* __restrict__ Wt,
    const float* __restrict__ bias, float* __restrict__ C)
{
    constexpr int BM = 128, BK = 32;
    __shared__ u16 sA0[BM * BK], sA1[BM * BK];
    __shared__ u16 sB0[BM * BK], sB1[BM * BK];

    const int tid  = threadIdx.x;
    const int wave = tid >> 6;
    const int lane = tid & 63;
    const int m0 = blockIdx.x * BM;
    const int n0 = blockIdx.y * BM;

    const int wrow = 64 * (wave >> 1);
    const int wcol = 64 * (wave & 1);

    f32x4 acc[4][4] = {};
    const int lr = lane & 15;
    const int kg = lane >> 4;
    const int kgs = ((kg ^ ((lr >> 1) & 3)) << 3);
    const int sgo = (((lane & 3) ^ ((lane >> 3) & 3)) << 3);

    float bv4[4];
#pragma unroll
    for (int j = 0; j < 4; ++j)
        bv4[j] = bias[n0 + wcol + j * 16 + lr];  // col <= 511, in-bounds

    const int cA = wave * 64 + lane;
    const size_t arow0 = (size_t)(m0 + (cA >> 2)) * DM + sgo;
    const int cA2 = (4 + wave) * 64 + lane;
    const size_t arow1 = (size_t)(m0 + (cA2 >> 2)) * DM + sgo;
    const size_t brow0 = (size_t)(n0 + (cA >> 2)) * DM + sgo;
    const size_t brow1 = (size_t)(n0 + (cA2 >> 2)) * DM + sgo;
    const int ldsA0 = wave * 512, ldsA1 = (4 + wave) * 512;

    auto stage = [&](u16* sa, u16* sb, int k0) {
        async_copy16(&sa[ldsA0], A + arow0 + k0);
        async_copy16(&sa[ldsA1], A + arow1 + k0);
        async_copy16(&sb[ldsA0], Wt + brow0 + k0);
        async_copy16(&sb[ldsA1], Wt + brow1 + k0);
    };

    stage(sA0, sB0, 0);

    for (int ktt = 0; ktt < 8; ++ktt) {
        stage(sA1, sB1, (2 * ktt + 1) << 5);
        VMW4_BARRIER();
        compute_phase(sA0, sB0, wrow, wcol, lr, kgs, acc);
        if (ktt < 7) {
            stage(sA0, sB0, (2 * ktt + 2) << 5);
            VMW4_BARRIER();
        } else {
            VMW0_BARRIER();
        }
        compute_phase(sA1, sB1, wrow, wcol, lr, kgs, acc);
    }

    const int crow0 = (lane >> 4) * 4;
#pragma unroll
    for (int i = 0; i < 4; ++i) {
#pragma unroll
        for (int j = 0; j < 4; ++j) {
            const int col = n0 + wcol + j * 16 + lr;
            const float bv = bv4[j];
#pragma unroll
            for (int r = 0; r < 4; ++r) {
                const int row = m0 + wrow + i * 16 + crow0 + r;
                C[(size_t)row * 512 + col] = acc[i][j][r] + bv;
            }
        }
    }
}

// ---------------------------------------------------------------------------
// Weight/bias prep + input pre-cast (fp32 -> bf16), one launch.
//   Wcat1 = [Wq; Woff; Wa] (576x512, alloc 768)   bcat1 = [bq; boff; ba]
//   Wcat2 = [Wk; Wv]       (1024x512)             bcat2 = [bk; bv]
//   Wob   = Wo
//   q_bf / kv_bf = bf16 casts of q_in / kv_in (8 floats -> ushort8 per thread)
// ---------------------------------------------------------------------------
__global__ __launch_bounds__(256) void prep_weights(
    const float* __restrict__ Wq, const float* __restrict__ Woff,
    const float* __restrict__ Wa, const float* __restrict__ Wk,
    const float* __restrict__ Wv, const float* __restrict__ Wo,
    const float* __restrict__ bq, const float* __restrict__ boff,
    const float* __restrict__ ba, const float* __restrict__ bk,
    const float* __restrict__ bv,
    const float* __restrict__ q_in, const float* __restrict__ kv_in,
    u16* __restrict__ Wcat1, u16* __restrict__ Wcat2, u16* __restrict__ Wob,
    float* __restrict__ bcat1, float* __restrict__ bcat2,
    u16* __restrict__ q_bf, u16* __restrict__ kv_bf, int n8)
{
    const int W4  = 65536;   // 512*512/4
    const int W4s = 4096;    // 32*512/4
    const int WEND = 4 * W4 + 2 * W4s;   // 270336
    const int BEND = WEND + 2048;        // bias section (padded)
    int tid = blockIdx.x * 256 + threadIdx.x;
    if (tid < WEND) {
        const float* src; u16* dst; int off;
        int t = tid;
        if (t < W4)                    { src = Wq;    dst = Wcat1;           off = t; }
        else if ((t -= W4) < W4s)      { src = Woff;  dst = Wcat1 + 262144;  off = t; }
        else if ((t -= W4s) < W4s)     { src = Wa;    dst = Wcat1 + 278528;  off = t; }
        else if ((t -= W4s) < W4)      { src = Wk;    dst = Wcat2;           off = t; }
        else if ((t -= W4) < W4)       { src = Wv;    dst = Wcat2 + 262144;  off = t; }
        else                           { src = Wo;    dst = Wob;             off = t - W4; }
        float4 v = ((const float4*)src)[off];
        ushort4 o;
        o.x = f2b(v.x); o.y = f2b(v.y); o.z = f2b(v.z); o.w = f2b(v.w);
        ((ushort4*)dst)[off] = o;
    } else if (tid < BEND) {
        int j = tid - WEND;
        if (j < 576) {
            bcat1[j] = (j < 512) ? bq[j] : (j < 544 ? boff[j - 512] : ba[j - 544]);
        } else if (j < 1600) {
            int j2 = j - 576;
            bcat2[j2] = (j2 < 512) ? bk[j2] : bv[j2 - 512];
        }
    } else {
        int t = tid - BEND;              // 0 .. 2*n8-1, each handles 8 floats
        if (t < 2 * n8) {
            const float* src; u16* dst; int off;
            if (t < n8) { src = q_in;  dst = q_bf;  off = t; }
            else        { src = kv_in; dst = kv_bf; off = t - n8; }
            float4 a = ((const float4*)src)[off * 2];
            float4 b = ((const float4*)src)[off * 2 + 1];
            uint4 w;
            w.x = pk2(a.x, a.y); w.y = pk2(a.z, a.w);
            w.z = pk2(b.x, b.y); w.w = pk2(b.z, b.w);
            ((uint4*)dst)[off] = w;
        }
    }
}

// ---------------------------------------------------------------------------
// Banded deformable attention. One wave per (b, h, 16-query block).
// k|v fused buffer: row stride 1024, k at cols 0..511, v at 512..1023.
// ---------------------------------------------------------------------------
__global__ __launch_bounds__(256) void deform_attn_band(
    const u16* __restrict__ q, const u16* __restrict__ kv,
    const float* __restrict__ offlog, u16* __restrict__ out, int B, int L)
{
    __shared__ u16  sVt[4][64 * 40];
    __shared__ float sS[4][16 * 36];
    __shared__ float sW[4][16 * 36];

    const int wave = threadIdx.x >> 6;
    const int lane = threadIdx.x & 63;
    const int gw = blockIdx.x * 4 + wave;     // over B*NH*(L/16)
    const int nlb = L >> 4;
    const int lblk = gw % nlb;
    const int bh = gw / nlb;
    const int h = bh % NH;
    const int b = bh / NH;
    const int l0 = lblk << 4;

    u16*  __restrict__ vt = sVt[wave];
    float* __restrict__ Ss = sS[wave];
    float* __restrict__ Ws = sW[wave];

    const size_t brow = (size_t)b * L;
    const int headoff = h * DD;

    const int l_loc = lane >> 2, p = lane & 3;
    const size_t obase = (brow + l0 + l_loc) * 64 + h * 4 + p;
    const float offv  = offlog[obase];
    const float logit = offlog[obase + 32];

    const int fr = lane & 15, kg = lane >> 4;

    const u16* qrow = q + (brow + l0 + fr) * DM + headoff;
    frag_ab qf0 = *(const frag_ab*)(qrow + kg * 8);
    frag_ab qf1 = *(const frag_ab*)(qrow + kg * 8 + 32);

    frag_ab kf[2][2];
#pragma unroll
    for (int jf = 0; jf < 2; ++jf) {
        int rr = l0 - 8 + jf * 16 + fr;
        rr = min(max(rr, 0), L - 1);
        const u16* krow = kv + (brow + rr) * 1024 + headoff;
        kf[jf][0] = *(const frag_ab*)(krow + kg * 8);
        kf[jf][1] = *(const frag_ab*)(krow + kg * 8 + 32);
    }

    const int vr = lane & 31, vd0 = (lane >> 5) * 32;
    int vrr = min(max(l0 - 8 + vr, 0), L - 1);
    const u16* vrow = kv + (brow + vrr) * 1024 + 512 + headoff + vd0;
    frag_ab vl[4];
#pragma unroll
    for (int i = 0; i < 4; ++i)
        vl[i] = *(const frag_ab*)(vrow + i * 8);

    f32x4 accS[2] = {};
#pragma unroll
    for (int jf = 0; jf < 2; ++jf) {
        accS[jf] = __builtin_amdgcn_mfma_f32_16x16x32_bf16(qf0, kf[jf][0], accS[jf], 0, 0, 0);
        accS[jf] = __builtin_amdgcn_mfma_f32_16x16x32_bf16(qf1, kf[jf][1], accS[jf], 0, 0, 0);
    }

#pragma unroll
    for (int i = 0; i < 4; ++i)
#pragma unroll
        for (int j = 0; j < 8; ++j)
            vt[(vd0 + i * 8 + j) * 40 + vr] = (u16)vl[i][j];

#pragma unroll
    for (int jf = 0; jf < 2; ++jf)
#pragma unroll
        for (int r = 0; r < 4; ++r)
            Ss[(kg * 4 + r) * 36 + jf * 16 + fr] = accS[jf][r];

#pragma unroll
    for (int i = 0; i < 9; ++i)
        Ws[lane + 64 * i] = 0.f;

    __syncthreads();

    float pos = fminf(fmaxf((float)(l0 + l_loc) + offv, 0.f), (float)(L - 1));
    float ff = floorf(pos);
    int i0 = (int)ff;
    float fw = pos - ff;
    int c0 = i0 - (l0 - 8);
    c0 = min(max(c0, 0), 30);
    float S0 = Ss[l_loc * 36 + c0];
    float S1 = Ss[l_loc * 36 + c0 + 1];
    float t = (S0 + fw * (S1 - S0)) * 0.125f + logit;
    float m1 = fmaxf(t, __shfl_xor(t, 1));
    float mx = fmaxf(m1, __shfl_xor(m1, 2));
    float e = __expf(t - mx);
    float s1 = e + __shfl_xor(e, 1);
    float ssum = s1 + __shfl_xor(s1, 2);
    float wgt = e * __builtin_amdgcn_rcpf(ssum);
    atomicAdd(&Ws[l_loc * 36 + c0], (1.f - fw) * wgt);
    atomicAdd(&Ws[l_loc * 36 + c0 + 1], fw * wgt);

    __syncthreads();

    float4 w0 = *(const float4*)&Ws[fr * 36 + kg * 8];
    float4 w1 = *(const float4*)&Ws[fr * 36 + kg * 8 + 4];
    frag_ab wf;
    wf[0] = (short)f2b(w0.x); wf[1] = (short)f2b(w0.y);
    wf[2] = (short)f2b(w0.z); wf[3] = (short)f2b(w0.w);
    wf[4] = (short)f2b(w1.x); wf[5] = (short)f2b(w1.y);
    wf[6] = (short)f2b(w1.z); wf[7] = (short)f2b(w1.w);

#pragma unroll
    for (int md = 0; md < 4; ++md) {
        frag_ab af = *(const frag_ab*)&vt[(md * 16 + fr) * 40 + kg * 8];
        f32x4 o = {};
        o = __builtin_amdgcn_mfma_f32_16x16x32_bf16(af, wf, o, 0, 0, 0);
        ushort4 pk;
        pk.x = f2b(o[0]); pk.y = f2b(o[1]); pk.z = f2b(o[2]); pk.w = f2b(o[3]);
        *(ushort4*)&out[(brow + l0 + fr) * DM + headoff + md * 16 + kg * 4] = pk;
    }
}

// ---------------------------------------------------------------------------
extern "C" void kernel_launch(void* const* d_in, const int* in_sizes, int n_in,
                              void* d_out, int out_size, void* d_ws, size_t ws_size,
                              hipStream_t stream) {
    const float* q_in  = (const float*)d_in[0];
    const float* kv_in = (const float*)d_in[1];
    const float* Wq = (const float*)d_in[2];  const float* bq = (const float*)d_in[3];
    const float* Wk = (const float*)d_in[4];  const float* bk = (const float*)d_in[5];
    const float* Wv = (const float*)d_in[6];  const float* bv = (const float*)d_in[7];
    const float* Woff=(const float*)d_in[8];  const float* boff=(const float*)d_in[9];
    const float* Wa = (const float*)d_in[10]; const float* ba = (const float*)d_in[11];
    const float* Wo = (const float*)d_in[12]; const float* bo = (const float*)d_in[13];

    const int M = in_sizes[0] / DM;     // B*L = 16384
    const int L = 4096;
    const int B = M / L;

    char* p = (char*)d_ws;
    u16* attn_o = (u16*)p;               p += (size_t)M * DM * 2;     // attention output
    u16* Wcat1  = (u16*)p;               p += (size_t)768 * DM * 2;   // 640 used; pad for OOB staging
    u16* Wcat2  = (u16*)p;               p += (size_t)1024 * DM * 2;
    u16* Wob    = (u16*)p;               p += (size_t)DM * DM * 2;
    float* bcat1= (float*)p;             p += 640 * 4;
    float* bcat2= (float*)p;             p += 1024 * 4;
    u16* q_ws   = (u16*)p;               p += (size_t)M * DM * 2;
    u16* kv_ws  = (u16*)p;               p += (size_t)M * 1024 * 2;   // k|v fused
    float* offlog = (float*)p;           p += (size_t)M * 64 * 4;

    // bf16 input casts — alias dead regions (same-stream serialization):
    //   q_bf  lives prep->proj; attn_o is only written later by deform_attn_band
    //   kv_bf lives prep->proj; d_out is only written later by out_gemm (fully)
    u16* q_bf  = attn_o;
    u16* kv_bf = (u16*)d_out;

    const int n8 = M * DM / 8;          // 8 floats per cast thread
    const int prep_threads = 4 * 65536 + 2 * 4096 + 2048 + 2 * n8;
    hipLaunchKernelGGL(prep_weights, dim3((prep_threads + 255) / 256), dim3(256), 0, stream,
                       Wq, Woff, Wa, Wk, Wv, Wo, bq, boff, ba, bk, bv,
                       q_in, kv_in,
                       Wcat1, Wcat2, Wob, bcat1, bcat2, q_bf, kv_bf, n8);

    // merged projections (all-bf16 async staging): y<5 -> q/off/a, y>=5 -> k|v
    hipLaunchKernelGGL(proj_gemm, dim3(M / 128, 13), dim3(256), 0, stream,
                       q_bf, kv_bf, Wcat1, Wcat2, bcat1, bcat2,
                       q_ws, offlog, kv_ws);

    // banded attention: 1 wave per (b,h,16 queries)
    int nwaves = B * NH * (L / 16);
    hipLaunchKernelGGL(deform_attn_band, dim3(nwaves / 4), dim3(256), 0, stream,
                       q_ws, kv_ws, offlog, attn_o, B, L);

    // output projection -> fp32 d_out
    hipLaunchKernelGGL(out_gemm, dim3(M / 128, 4), dim3(256), 0, stream,
                       attn_o, Wob, bo, (float*)d_out);
}